// Round 2
// baseline (11264.951 us; speedup 1.0000x reference)
//
#include <hip/hip_runtime.h>

#define B_   64
#define T_   512
#define NE   1024
#define ND   512

// ---------------- ws layout (floats) ----------------
#define WS_TH0   0         // th buffer 0: [64][1024]
#define WS_TH1   65536     // th buffer 1
#define WS_LAST  131072    // last_enc [64][1024]
#define WS_BAR   196608    // barrier: unsigned cnt[8] (stride 32), flag at +256
#define WS_ZERO_F4 49280   // (196608 + 512) / 4 float4s to zero

__global__ __launch_bounds__(256) void init_ws(float4* __restrict__ ws4) {
    int i = blockIdx.x * 256 + threadIdx.x;
    if (i < WS_ZERO_F4) ws4[i] = make_float4(0.f, 0.f, 0.f, 0.f);
}

// Persistent encoder: 256 blocks (1/CU), 512 threads.
// Block (pb = bid>>4, ng = bid&15) owns batches [pb*4,+4), neurons [ng*64,+64).
// Thread (ks = tid>>4 in [0,32), ng4 = tid&15): tile 4n x 4b x 32k, J in regs.
// k-columns of thread = { ks*4 + j*128 + i : j in [0,8), i in [0,4) }.
__global__ __launch_bounds__(512, 2)
void enc_persist(const float* __restrict__ X, const float* __restrict__ noise,
                 const float* __restrict__ W_in, const float* __restrict__ J,
                 const float* __restrict__ in_s, const int* __restrict__ BT,
                 float* __restrict__ th0, float* __restrict__ th1,
                 float* __restrict__ last, unsigned* __restrict__ bar)
{
    __shared__ float th_lds[4096];   // 4 batches x 1024 (row stride 1024)
    __shared__ float red[8352];      // [ks 32]*261 + [b 4]*65 + [n 64]

    const int tid = threadIdx.x;
    const int bid = blockIdx.x;
    const int pb  = bid >> 4;          // batch group (4 batches)
    const int nb  = (bid & 15) * 64;   // neuron base
    const int ks  = tid >> 4;          // 0..31  k-slice
    const int ng4 = tid & 15;          // 0..15  4-neuron subgroup
    const int ks4 = ks * 4;

    // ---- J fragment -> 128 VGPRs (static across all 511 steps) ----
    float4 Jr[4][8];
    #pragma unroll
    for (int ni = 0; ni < 4; ++ni) {
        const float* Jp = J + (size_t)(nb + ng4 * 4 + ni) * NE + ks4;
        #pragma unroll
        for (int j = 0; j < 8; ++j)
            Jr[ni][j] = *(const float4*)(Jp + j * 128);
    }

    // ---- owner state (tid < 256 owns h[bg][ng_]) ----
    const int bo  = tid >> 6;          // 0..3
    const int nl  = tid & 63;          // 0..63
    const int bg  = pb * 4 + bo;
    const int ng_ = nb + nl;
    float hreg = 0.f, w0 = 0.f, w1 = 0.f;
    int bt = -999;
    const float is0 = in_s[0], is1 = in_s[1];
    if (tid < 256) {
        w0 = W_in[ng_ * 2 + 0];
        w1 = W_in[ng_ * 2 + 1];
        bt = BT[bg];
    }

    unsigned* cnt  = bar;              // 8 counters, stride 32 (128B apart)
    unsigned* flag = bar + 256;

    for (int t = 0; t < T_ - 1; ++t) {
        const float* __restrict__ cur = (t & 1) ? th1 : th0;
        float*       __restrict__ nxt = (t & 1) ? th0 : th1;

        // ---- gate: wait for all th_t writes, then invalidate caches ----
        if (t > 0) {
            if (tid == 0 && bid != 0) {
                while (__hip_atomic_load(flag, __ATOMIC_RELAXED,
                                         __HIP_MEMORY_SCOPE_AGENT) < (unsigned)t)
                    __builtin_amdgcn_s_sleep(1);
            }
            __syncthreads();
            __builtin_amdgcn_fence(__ATOMIC_ACQUIRE, "agent");
        }

        // ---- prefetch drive terms (hidden under MAC) ----
        float nz = 0.f, xa = 0.f, xb = 0.f;
        if (tid < 256) {
            nz = noise[((size_t)bg * T_ + t) * NE + ng_];
            xa = X[((size_t)bg * T_ + t) * 2 + 0];
            xb = X[((size_t)bg * T_ + t) * 2 + 1];
        }

        // ---- stage th tile: 4 rows x 1024 = 16KB ----
        {
            const float4* src = (const float4*)(cur + (size_t)pb * 4096);
            float4 v0 = src[tid], v1 = src[tid + 512];
            ((float4*)th_lds)[tid]       = v0;
            ((float4*)th_lds)[tid + 512] = v1;
        }
        __syncthreads();

        // ---- MAC: 512 fma, 32 LDS b128 reads (4 addr / 16-lane bcast) ----
        float acc[4][4] = {};
        #pragma unroll
        for (int j = 0; j < 8; ++j) {
            #pragma unroll
            for (int b = 0; b < 4; ++b) {
                float4 tv = *(const float4*)&th_lds[b * 1024 + ks4 + j * 128];
                #pragma unroll
                for (int ni = 0; ni < 4; ++ni) {
                    acc[b][ni] = fmaf(Jr[ni][j].x, tv.x, acc[b][ni]);
                    acc[b][ni] = fmaf(Jr[ni][j].y, tv.y, acc[b][ni]);
                    acc[b][ni] = fmaf(Jr[ni][j].z, tv.z, acc[b][ni]);
                    acc[b][ni] = fmaf(Jr[ni][j].w, tv.w, acc[b][ni]);
                }
            }
        }

        // ---- K-reduction: write partials (2-way bank aliasing = free) ----
        #pragma unroll
        for (int b = 0; b < 4; ++b)
            #pragma unroll
            for (int ni = 0; ni < 4; ++ni)
                red[ks * 261 + b * 65 + ng4 * 4 + ni] = acc[b][ni];
        __syncthreads();

        // ---- reduce 32 partials + h update (owners) ----
        if (tid < 256) {
            float s = 0.f;
            #pragma unroll
            for (int k = 0; k < 32; ++k)
                s += red[k * 261 + bo * 65 + nl];
            float drive = s + nz + xa * is0 * w0 + xb * is1 * w1;
            hreg = 0.9f * hreg + 0.1f * drive;
            nxt[(size_t)bg * NE + ng_] = tanhf(hreg);
            if (bt == t + 1) last[(size_t)bg * NE + ng_] = hreg;
        }
        __syncthreads();

        // ---- arrive (release: L2 writeback before count) ----
        if (tid == 0)
            __hip_atomic_fetch_add(&cnt[(bid & 7) * 32], 1u,
                                   __ATOMIC_RELEASE, __HIP_MEMORY_SCOPE_AGENT);
        if (bid == 0 && tid == 0) {
            const unsigned target = 256u * (unsigned)(t + 1);
            for (;;) {
                unsigned s = 0;
                #pragma unroll
                for (int i = 0; i < 8; ++i)
                    s += __hip_atomic_load(&cnt[i * 32], __ATOMIC_RELAXED,
                                           __HIP_MEMORY_SCOPE_AGENT);
                if (s >= target) break;
                __builtin_amdgcn_s_sleep(1);
            }
            __hip_atomic_store(flag, (unsigned)(t + 1),
                               __ATOMIC_RELEASE, __HIP_MEMORY_SCOPE_AGENT);
        }
    }
}

// ---- tail (unchanged from round 1, reads last at new offset) ----
__global__ __launch_bounds__(256)
void wproj(const float* __restrict__ last_enc, const float* __restrict__ W,
           const float* __restrict__ bW, float* __restrict__ dec_traj)
{
    __shared__ float tl[NE];
    const int b = blockIdx.x;
    for (int k = threadIdx.x; k < NE; k += 256)
        tl[k] = tanhf(last_enc[(size_t)b * NE + k]);
    __syncthreads();
    const int wave = threadIdx.x >> 6;
    const int lane = threadIdx.x & 63;
    for (int m = wave; m < ND; m += 4) {
        const float4* Wr = (const float4*)(W + (size_t)m * NE);
        float acc = 0.f;
        #pragma unroll
        for (int it = 0; it < 4; ++it) {
            float4 wv = Wr[lane + it * 64];
            const float* tp = &tl[(lane + it * 64) * 4];
            acc = fmaf(wv.x, tp[0], acc);
            acc = fmaf(wv.y, tp[1], acc);
            acc = fmaf(wv.z, tp[2], acc);
            acc = fmaf(wv.w, tp[3], acc);
        }
        acc += __shfl_down(acc, 32); acc += __shfl_down(acc, 16);
        acc += __shfl_down(acc, 8);  acc += __shfl_down(acc, 4);
        acc += __shfl_down(acc, 2);  acc += __shfl_down(acc, 1);
        if (lane == 0) dec_traj[(size_t)b * 4 * ND + m] = acc + bW[m];
    }
}

__global__ __launch_bounds__(256)
void dec_step(const float* __restrict__ Q, float* __restrict__ dec_traj, int s)
{
    __shared__ float prev[ND];
    const int b = blockIdx.x;
    const float* pin = dec_traj + (size_t)b * 4 * ND + (size_t)(s - 1) * ND;
    for (int k = threadIdx.x; k < ND; k += 256) prev[k] = pin[k];
    __syncthreads();
    const int wave = threadIdx.x >> 6;
    const int lane = threadIdx.x & 63;
    for (int m = wave; m < ND; m += 4) {
        const float4* Qr = (const float4*)(Q + (size_t)m * ND);
        float acc = 0.f;
        #pragma unroll
        for (int it = 0; it < 2; ++it) {
            float4 qv = Qr[lane + it * 64];
            const float* tp = &prev[(lane + it * 64) * 4];
            acc = fmaf(qv.x, tp[0], acc);
            acc = fmaf(qv.y, tp[1], acc);
            acc = fmaf(qv.z, tp[2], acc);
            acc = fmaf(qv.w, tp[3], acc);
        }
        acc += __shfl_down(acc, 32); acc += __shfl_down(acc, 16);
        acc += __shfl_down(acc, 8);  acc += __shfl_down(acc, 4);
        acc += __shfl_down(acc, 2);  acc += __shfl_down(acc, 1);
        if (lane == 0)
            dec_traj[(size_t)b * 4 * ND + (size_t)s * ND + m] = acc;
    }
}

__global__ __launch_bounds__(256)
void out_proj(const float* __restrict__ dec_traj, const float* __restrict__ W_out,
              const float* __restrict__ out_s, float* __restrict__ Out)
{
    const int b = blockIdx.x;
    const int s = threadIdx.x >> 6;
    const int lane = threadIdx.x & 63;
    const float4* dp = (const float4*)(dec_traj + (size_t)b * 4 * ND + (size_t)s * ND);
    const float4* w0 = (const float4*)(W_out);
    const float4* w1 = (const float4*)(W_out + ND);
    float a0 = 0.f, a1 = 0.f;
    #pragma unroll
    for (int it = 0; it < 2; ++it) {
        float4 v  = dp[lane + it * 64];
        float4 u0 = w0[lane + it * 64];
        float4 u1 = w1[lane + it * 64];
        a0 = fmaf(v.x, u0.x, fmaf(v.y, u0.y, fmaf(v.z, u0.z, fmaf(v.w, u0.w, a0))));
        a1 = fmaf(v.x, u1.x, fmaf(v.y, u1.y, fmaf(v.z, u1.z, fmaf(v.w, u1.w, a1))));
    }
    for (int off = 32; off; off >>= 1) {
        a0 += __shfl_down(a0, off);
        a1 += __shfl_down(a1, off);
    }
    if (lane == 0) {
        Out[(size_t)b * 8 + s * 2 + 0] = out_s[0] * a0;
        Out[(size_t)b * 8 + s * 2 + 1] = out_s[1] * a1;
    }
}

extern "C" void kernel_launch(void* const* d_in, const int* in_sizes, int n_in,
                              void* d_out, int out_size, void* d_ws, size_t ws_size,
                              hipStream_t stream) {
    const float* X      = (const float*)d_in[0];
    const float* noise  = (const float*)d_in[1];
    const float* W_in   = (const float*)d_in[2];
    const float* J      = (const float*)d_in[3];
    const float* W      = (const float*)d_in[4];
    const float* bW     = (const float*)d_in[5];
    const float* Q      = (const float*)d_in[6];
    const float* W_out  = (const float*)d_in[7];
    const float* in_s   = (const float*)d_in[8];
    const float* out_s  = (const float*)d_in[9];
    const int*   BT     = (const int*)d_in[10];

    float* ws   = (float*)d_ws;
    float* th0  = ws + WS_TH0;
    float* th1  = ws + WS_TH1;
    float* last = ws + WS_LAST;
    unsigned* bar = (unsigned*)(ws + WS_BAR);

    float* out      = (float*)d_out;               // dec_traj (64,4,512)
    float* out_tail = out + (size_t)B_ * 4 * ND;   // Output (64,4,2)

    init_ws<<<193, 256, 0, stream>>>((float4*)ws);
    enc_persist<<<256, 512, 0, stream>>>(X, noise, W_in, J, in_s, BT,
                                         th0, th1, last, bar);
    wproj<<<B_, 256, 0, stream>>>(last, W, bW, out);
    for (int s = 1; s <= 3; ++s)
        dec_step<<<B_, 256, 0, stream>>>(Q, out, s);
    out_proj<<<B_, 256, 0, stream>>>(out, W_out, out_s, out_tail);
}

// Round 3
// 3299.512 us; speedup vs baseline: 3.4141x; 3.4141x over previous
//
#include <hip/hip_runtime.h>

#define B_   64
#define T_   512
#define NE   1024
#define ND   512

// ---------------- ws layout (floats) ----------------
#define WS_TH0   0         // th buffer 0: [64][1024]
#define WS_TH1   65536     // th buffer 1
#define WS_LAST  131072    // last_enc [64][1024]
#define WS_BAR   196608    // 16 group counters, stride 32 uints (128B)
#define WS_ZERO_F4 49280   // zero th0,th1,last,bar

__global__ __launch_bounds__(256) void init_ws(float4* __restrict__ ws4) {
    int i = blockIdx.x * 256 + threadIdx.x;
    if (i < WS_ZERO_F4) ws4[i] = make_float4(0.f, 0.f, 0.f, 0.f);
}

// Persistent encoder: 256 blocks (1/CU), 512 threads.
// Block (pb = bid>>4, ng = bid&15): batches [pb*4,+4), neurons [ng*64,+64).
// Thread (ks = tid>>4, ng4 = tid&15): 4n x 4b x (32 scattered float4 k-cols),
// J fragment pinned in 128 VGPRs. Sync: per-pb-group (16 blocks) counter via
// agent-scope atomics at LLC; th exchanged via agent atomics (bypass stale L2).
__global__ __launch_bounds__(512, 2)
void enc_persist(const float* __restrict__ X, const float* __restrict__ noise,
                 const float* __restrict__ W_in, const float* __restrict__ J,
                 const float* __restrict__ in_s, const int* __restrict__ BT,
                 float* __restrict__ th0, float* __restrict__ th1,
                 float* __restrict__ last, unsigned* __restrict__ bar)
{
    __shared__ float th_lds[4096];    // 4 batches x 1024
    __shared__ float red[8700];       // [ks]*272 + [b]*68 + [n 0..63]

    const int tid = threadIdx.x;
    const int bid = blockIdx.x;
    const int pb  = bid >> 4;          // 0..15 batch group
    const int nb  = (bid & 15) * 64;   // neuron base
    const int ks  = tid >> 4;          // 0..31
    const int ng4 = tid & 15;          // 0..15
    const int ks4 = ks * 4;

    // ---- J fragment -> 128 VGPRs, pinned (opaque to rematerialization) ----
    float Jreg[128];
    #pragma unroll
    for (int ni = 0; ni < 4; ++ni) {
        const float* Jp = J + (size_t)(nb + ng4 * 4 + ni) * NE + ks4;
        #pragma unroll
        for (int j = 0; j < 8; ++j) {
            float4 v = *(const float4*)(Jp + j * 128);
            Jreg[ni * 32 + j * 4 + 0] = v.x;
            Jreg[ni * 32 + j * 4 + 1] = v.y;
            Jreg[ni * 32 + j * 4 + 2] = v.z;
            Jreg[ni * 32 + j * 4 + 3] = v.w;
        }
    }
    #pragma unroll
    for (int i = 0; i < 128; ++i)
        asm volatile("" : "+v"(Jreg[i]));

    // ---- owner state (tid < 256 owns h[bg][ng_]) ----
    const int bo  = tid >> 6;
    const int nl  = tid & 63;
    const int bg  = pb * 4 + bo;
    const int ng_ = nb + nl;
    float hreg = 0.f, w0 = 0.f, w1 = 0.f;
    int bt = -999;
    const float is0 = in_s[0], is1 = in_s[1];
    if (tid < 256) {
        w0 = W_in[ng_ * 2 + 0];
        w1 = W_in[ng_ * 2 + 1];
        bt = BT[bg];
    }

    // group step count: max BT of the 4 batches in this group
    const int m = max(max(BT[pb * 4 + 0], BT[pb * 4 + 1]),
                      max(BT[pb * 4 + 2], BT[pb * 4 + 3]));

    unsigned* cnt = bar + pb * 32;     // group counter, own 128B line

    for (int t = 0; t < m; ++t) {
        float* __restrict__ cur = (t & 1) ? th1 : th0;
        float* __restrict__ nxt = (t & 1) ? th0 : th1;

        // ---- gate: wait for the 16 group blocks to finish step t-1 ----
        if (t > 0) {
            if (tid == 0) {
                const unsigned tgt = 16u * (unsigned)t;
                while (__hip_atomic_load(cnt, __ATOMIC_RELAXED,
                                         __HIP_MEMORY_SCOPE_AGENT) < tgt)
                    __builtin_amdgcn_s_sleep(1);
            }
            __syncthreads();
        }

        // ---- prefetch drive terms (plain loads, read-only inputs) ----
        float nz = 0.f, xa = 0.f, xb = 0.f;
        if (tid < 256) {
            nz = noise[((size_t)bg * T_ + t) * NE + ng_];
            xa = X[((size_t)bg * T_ + t) * 2 + 0];
            xb = X[((size_t)bg * T_ + t) * 2 + 1];
        }

        // ---- stage th tile (16KB) via LLC-coherent loads ----
        {
            const float* src = cur + (size_t)pb * 4096;
            #pragma unroll
            for (int j = 0; j < 8; ++j) {
                float v = __hip_atomic_load(src + tid + j * 512,
                                            __ATOMIC_RELAXED,
                                            __HIP_MEMORY_SCOPE_AGENT);
                th_lds[tid + j * 512] = v;
            }
        }
        __syncthreads();

        // ---- MAC: 512 fma vs pinned J, LDS reads are 16-lane broadcasts ----
        float acc[4][4] = {};
        #pragma unroll
        for (int j = 0; j < 8; ++j) {
            #pragma unroll
            for (int b = 0; b < 4; ++b) {
                float4 tv = *(const float4*)&th_lds[b * 1024 + ks4 + j * 128];
                #pragma unroll
                for (int ni = 0; ni < 4; ++ni) {
                    acc[b][ni] = fmaf(Jreg[ni * 32 + j * 4 + 0], tv.x, acc[b][ni]);
                    acc[b][ni] = fmaf(Jreg[ni * 32 + j * 4 + 1], tv.y, acc[b][ni]);
                    acc[b][ni] = fmaf(Jreg[ni * 32 + j * 4 + 2], tv.z, acc[b][ni]);
                    acc[b][ni] = fmaf(Jreg[ni * 32 + j * 4 + 3], tv.w, acc[b][ni]);
                }
            }
        }

        // ---- K-reduction partials (16B-aligned rows -> ds_write_b128) ----
        #pragma unroll
        for (int b = 0; b < 4; ++b)
            #pragma unroll
            for (int ni = 0; ni < 4; ++ni)
                red[ks * 272 + b * 68 + ng4 * 4 + ni] = acc[b][ni];
        __syncthreads();

        // ---- owners: reduce 32, update h, publish tanh(h) to LLC ----
        if (tid < 256) {
            float s = 0.f;
            #pragma unroll
            for (int k = 0; k < 32; ++k)
                s += red[k * 272 + bo * 68 + nl];
            float drive = s + nz + xa * is0 * w0 + xb * is1 * w1;
            hreg = 0.9f * hreg + 0.1f * drive;
            __hip_atomic_store(nxt + (size_t)bg * NE + ng_, tanhf(hreg),
                               __ATOMIC_RELAXED, __HIP_MEMORY_SCOPE_AGENT);
            if (bt == t + 1) last[(size_t)bg * NE + ng_] = hreg;
        }
        __syncthreads();   // drains vmcnt: th stores at LLC before arrive

        // ---- arrive ----
        if (tid == 0)
            __hip_atomic_fetch_add(cnt, 1u, __ATOMIC_RELEASE,
                                   __HIP_MEMORY_SCOPE_AGENT);
    }
}

// ---- tail ----
__global__ __launch_bounds__(256)
void wproj(const float* __restrict__ last_enc, const float* __restrict__ W,
           const float* __restrict__ bW, float* __restrict__ dec_traj)
{
    __shared__ float tl[NE];
    const int b = blockIdx.x;
    for (int k = threadIdx.x; k < NE; k += 256)
        tl[k] = tanhf(last_enc[(size_t)b * NE + k]);
    __syncthreads();
    const int wave = threadIdx.x >> 6;
    const int lane = threadIdx.x & 63;
    for (int m = wave; m < ND; m += 4) {
        const float4* Wr = (const float4*)(W + (size_t)m * NE);
        float acc = 0.f;
        #pragma unroll
        for (int it = 0; it < 4; ++it) {
            float4 wv = Wr[lane + it * 64];
            const float* tp = &tl[(lane + it * 64) * 4];
            acc = fmaf(wv.x, tp[0], acc);
            acc = fmaf(wv.y, tp[1], acc);
            acc = fmaf(wv.z, tp[2], acc);
            acc = fmaf(wv.w, tp[3], acc);
        }
        acc += __shfl_down(acc, 32); acc += __shfl_down(acc, 16);
        acc += __shfl_down(acc, 8);  acc += __shfl_down(acc, 4);
        acc += __shfl_down(acc, 2);  acc += __shfl_down(acc, 1);
        if (lane == 0) dec_traj[(size_t)b * 4 * ND + m] = acc + bW[m];
    }
}

__global__ __launch_bounds__(256)
void dec_step(const float* __restrict__ Q, float* __restrict__ dec_traj, int s)
{
    __shared__ float prev[ND];
    const int b = blockIdx.x;
    const float* pin = dec_traj + (size_t)b * 4 * ND + (size_t)(s - 1) * ND;
    for (int k = threadIdx.x; k < ND; k += 256) prev[k] = pin[k];
    __syncthreads();
    const int wave = threadIdx.x >> 6;
    const int lane = threadIdx.x & 63;
    for (int m = wave; m < ND; m += 4) {
        const float4* Qr = (const float4*)(Q + (size_t)m * ND);
        float acc = 0.f;
        #pragma unroll
        for (int it = 0; it < 2; ++it) {
            float4 qv = Qr[lane + it * 64];
            const float* tp = &prev[(lane + it * 64) * 4];
            acc = fmaf(qv.x, tp[0], acc);
            acc = fmaf(qv.y, tp[1], acc);
            acc = fmaf(qv.z, tp[2], acc);
            acc = fmaf(qv.w, tp[3], acc);
        }
        acc += __shfl_down(acc, 32); acc += __shfl_down(acc, 16);
        acc += __shfl_down(acc, 8);  acc += __shfl_down(acc, 4);
        acc += __shfl_down(acc, 2);  acc += __shfl_down(acc, 1);
        if (lane == 0)
            dec_traj[(size_t)b * 4 * ND + (size_t)s * ND + m] = acc;
    }
}

__global__ __launch_bounds__(256)
void out_proj(const float* __restrict__ dec_traj, const float* __restrict__ W_out,
              const float* __restrict__ out_s, float* __restrict__ Out)
{
    const int b = blockIdx.x;
    const int s = threadIdx.x >> 6;
    const int lane = threadIdx.x & 63;
    const float4* dp = (const float4*)(dec_traj + (size_t)b * 4 * ND + (size_t)s * ND);
    const float4* w0 = (const float4*)(W_out);
    const float4* w1 = (const float4*)(W_out + ND);
    float a0 = 0.f, a1 = 0.f;
    #pragma unroll
    for (int it = 0; it < 2; ++it) {
        float4 v  = dp[lane + it * 64];
        float4 u0 = w0[lane + it * 64];
        float4 u1 = w1[lane + it * 64];
        a0 = fmaf(v.x, u0.x, fmaf(v.y, u0.y, fmaf(v.z, u0.z, fmaf(v.w, u0.w, a0))));
        a1 = fmaf(v.x, u1.x, fmaf(v.y, u1.y, fmaf(v.z, u1.z, fmaf(v.w, u1.w, a1))));
    }
    for (int off = 32; off; off >>= 1) {
        a0 += __shfl_down(a0, off);
        a1 += __shfl_down(a1, off);
    }
    if (lane == 0) {
        Out[(size_t)b * 8 + s * 2 + 0] = out_s[0] * a0;
        Out[(size_t)b * 8 + s * 2 + 1] = out_s[1] * a1;
    }
}

extern "C" void kernel_launch(void* const* d_in, const int* in_sizes, int n_in,
                              void* d_out, int out_size, void* d_ws, size_t ws_size,
                              hipStream_t stream) {
    const float* X      = (const float*)d_in[0];
    const float* noise  = (const float*)d_in[1];
    const float* W_in   = (const float*)d_in[2];
    const float* J      = (const float*)d_in[3];
    const float* W      = (const float*)d_in[4];
    const float* bW     = (const float*)d_in[5];
    const float* Q      = (const float*)d_in[6];
    const float* W_out  = (const float*)d_in[7];
    const float* in_s   = (const float*)d_in[8];
    const float* out_s  = (const float*)d_in[9];
    const int*   BT     = (const int*)d_in[10];

    float* ws   = (float*)d_ws;
    float* th0  = ws + WS_TH0;
    float* th1  = ws + WS_TH1;
    float* last = ws + WS_LAST;
    unsigned* bar = (unsigned*)(ws + WS_BAR);

    float* out      = (float*)d_out;               // dec_traj (64,4,512)
    float* out_tail = out + (size_t)B_ * 4 * ND;   // Output (64,4,2)

    init_ws<<<193, 256, 0, stream>>>((float4*)ws);
    enc_persist<<<256, 512, 0, stream>>>(X, noise, W_in, J, in_s, BT,
                                         th0, th1, last, bar);
    wproj<<<B_, 256, 0, stream>>>(last, W, bW, out);
    for (int s = 1; s <= 3; ++s)
        dec_step<<<B_, 256, 0, stream>>>(Q, out, s);
    out_proj<<<B_, 256, 0, stream>>>(out, W_out, out_s, out_tail);
}